// Round 5
// baseline (82.423 us; speedup 1.0000x reference)
//
#include <hip/hip_runtime.h>

// SGNN projection, round 5: tail-free grid, 2 outputs/lane sharing one seed.
//
// Math (M = 2^31-1 Mersenne, HALF = 2^30-1):
//   centered(v) = ((v + HALF) mod M) - HALF  ->  p2 = sig*seed + HALF (one v_mad_u64_u32).
//   Masked slots (sig=0 -> residue HALF) contribute 0 after the linear -HALF,
//   hoisted to a single -128*HALF.
//   Fold: s = (p2>>31) + (p2 & M) <= 2^32-4 < 2M ALWAYS (sig,seed <= 2^31-2), so
//   residue = s - M*[s>=M] exactly. Accumulate sum(s) u64 + q = count[s>=M];
//   centered partial = sum - M*q - 128*HALF, exact int64.
//
// Grid: 1344 blocks x 256 = 344064 lanes, each lane does t and t+344064.
// 344064 = 672*512 -> same h (same seed, same partition), b' = b+512.
// 1344 blocks = 5.25/CU < 8/CU residency cap -> fully co-resident, zero tail,
// perfectly uniform work, 4 independent accumulator chains per lane.

#define M31    2147483647u   // 2^31 - 1
#define HALF_B 1073741823u   // 2^30 - 1

__global__ __launch_bounds__(64) void sgnn_prep_kernel(
    const int* __restrict__ sig,    // [3, B, 128]
    const int* __restrict__ mask,   // [3, B, 128]
    unsigned* __restrict__ msig,    // [3, B, 128] mask-zeroed
    float* __restrict__ invc)       // [3, B]  = 1/(max(cnt,1)*HALF)
{
    const int row = blockIdx.x;          // p*nbatch + b
    const int t   = threadIdx.x;
    const int g0  = row * 128 + t;
    const int g1  = g0 + 64;
    const int mk0 = mask[g0], mk1 = mask[g1];
    msig[g0] = mk0 ? (unsigned)sig[g0] : 0u;
    msig[g1] = mk1 ? (unsigned)sig[g1] : 0u;
    const unsigned long long b0 = __ballot(mk0 != 0);
    const unsigned long long b1 = __ballot(mk1 != 0);
    if (t == 0) {
        int c = __popcll(b0) + __popcll(b1);
        if (c < 1) c = 1;
        invc[row] = 1.0f / ((float)c * 1073741823.0f);
    }
}

__device__ __forceinline__ void acc_elem(unsigned v, unsigned seed,
                                         unsigned long long& sum, unsigned& q) {
    const unsigned long long p2 =
        (unsigned long long)v * (unsigned long long)seed + (unsigned long long)HALF_B;
    const unsigned lo = (unsigned)p2;
    const unsigned hi = (unsigned)(p2 >> 32);
    const unsigned s  = __builtin_amdgcn_alignbit(hi, lo, 31) + (lo & 0x7FFFFFFFu);
    q   += (s >= M31);
    sum += s;
}

__global__ __launch_bounds__(256, 8) void sgnn_main_kernel(
    const unsigned* __restrict__ msig,  // [3, B, 128]
    const float* __restrict__ invc,     // [3, B]
    const int* __restrict__ seeds,      // [672]
    float* __restrict__ out,            // [B, 672] == flat[t]
    int nbatch)
{
    const unsigned t = blockIdx.x * 256u + threadIdx.x;  // [0, 344064)
    // b = floor(t/672) = floor((t>>5)/21), exact for t < 2^21 via magic 99865 = ceil(2^21/21)
    const unsigned x = t >> 5;
    const unsigned b = (x * 99865u) >> 21;
    const unsigned h = t - 672u * b;
    const int p = (h < 112u) ? 0 : (h < 336u) ? 1 : 2;

    const unsigned rowbase = (unsigned)(p * nbatch) + b;        // p*nbatch + b
    const unsigned* __restrict__ rp0 = msig + rowbase * 128u;   // output 0: (p, b)
    const unsigned* __restrict__ rp1 = rp0 + 512u * 128u;       // output 1: (p, b+512)
    const unsigned seed = (unsigned)seeds[h];

    unsigned long long sA0 = 0, sA1 = 0, sB0 = 0, sB1 = 0;  // 4 independent chains
    unsigned qA0 = 0, qA1 = 0, qB0 = 0, qB1 = 0;

    #pragma unroll 2
    for (int mm = 0; mm < 128; mm += 8) {
        const uint4 a = *(const uint4*)(rp0 + mm);
        const uint4 c = *(const uint4*)(rp0 + mm + 4);
        const uint4 d = *(const uint4*)(rp1 + mm);
        const uint4 e = *(const uint4*)(rp1 + mm + 4);
        acc_elem(a.x, seed, sA0, qA0); acc_elem(a.y, seed, sA1, qA1);
        acc_elem(a.z, seed, sA0, qA0); acc_elem(a.w, seed, sA1, qA1);
        acc_elem(c.x, seed, sA0, qA0); acc_elem(c.y, seed, sA1, qA1);
        acc_elem(c.z, seed, sA0, qA0); acc_elem(c.w, seed, sA1, qA1);
        acc_elem(d.x, seed, sB0, qB0); acc_elem(d.y, seed, sB1, qB1);
        acc_elem(d.z, seed, sB0, qB0); acc_elem(d.w, seed, sB1, qB1);
        acc_elem(e.x, seed, sB0, qB0); acc_elem(e.y, seed, sB1, qB1);
        acc_elem(e.z, seed, sB0, qB0); acc_elem(e.w, seed, sB1, qB1);
    }

    const long long cA = (long long)(sA0 + sA1)
                       - (long long)(qA0 + qA1) * 2147483647LL
                       - 128LL * 1073741823LL;
    const long long cB = (long long)(sB0 + sB1)
                       - (long long)(qB0 + qB1) * 2147483647LL
                       - 128LL * 1073741823LL;
    const float ivA = invc[rowbase];
    const float ivB = invc[rowbase + 512u];
    out[t]           = (float)cA * ivA;
    out[t + 344064u] = (float)cB * ivB;
}

extern "C" void kernel_launch(void* const* d_in, const int* in_sizes, int n_in,
                              void* d_out, int out_size, void* d_ws, size_t ws_size,
                              hipStream_t stream) {
    const int* sig   = (const int*)d_in[0];
    const int* mask  = (const int*)d_in[1];
    const int* seeds = (const int*)d_in[2];
    float* out = (float*)d_out;

    const int nbatch = in_sizes[0] / (3 * 128);        // 1024
    unsigned* msig = (unsigned*)d_ws;                   // 3*nbatch*128 u32
    float* invc = (float*)((char*)d_ws + (size_t)(3 * nbatch * 128) * 4);  // 3*nbatch f32

    sgnn_prep_kernel<<<dim3(3 * nbatch), dim3(64), 0, stream>>>(sig, mask, msig, invc);
    // 1344 blocks x 256 lanes x 2 outputs = 688128 = nbatch*672 exactly
    sgnn_main_kernel<<<dim3(1344), dim3(256), 0, stream>>>(msig, invc, seeds, out, nbatch);
}

// Round 6
// 76.527 us; speedup vs baseline: 1.0770x; 1.0770x over previous
//
#include <hip/hip_runtime.h>

// SGNN projection, round 6: mask-compacted rows (-25% elements).
//
// Math (M = 2^31-1 Mersenne, HALF = 2^30-1):
//   centered(v) = ((v + HALF) mod M) - HALF  ->  p2 = sig*seed + HALF (one v_mad_u64_u32).
//   Fold: s = (p2>>31) + (p2 & M) <= 2^32-4 < 2M ALWAYS (sig,seed <= 2^31-2), so
//   residue = s - M*[s>=M] exactly. centered partial = sum(s) - M*q - n*HALF, exact int64.
//   Pad-zero slots (sig=0) give s = HALF exactly, removed by the n*HALF term.
//
// Compaction: mask is ~70% dense; prep packs valid sigs to the row front via
// ballot prefix-sum, zero-pads to cnt16 = ceil(cnt/16)*16, stores cnt16 + invc.
// Main loops only cnt16 elements (~96 avg vs 128). Sum over a permuted subset
// is identical -> still exact. Waves are row-uniform except the two p-boundary
// waves per 672-block (1 extra masked iteration at most).

#define M31    2147483647u   // 2^31 - 1
#define HALF_B 1073741823u   // 2^30 - 1

__global__ __launch_bounds__(64) void sgnn_prep_kernel(
    const int* __restrict__ sig,    // [3, B, 128]
    const int* __restrict__ mask,   // [3, B, 128]
    unsigned* __restrict__ msig,    // [3, B, 128] compacted, zero-padded to cnt16
    float* __restrict__ invc,       // [3, B] = 1/(max(cnt,1)*HALF)
    unsigned* __restrict__ cnt16)   // [3, B] = ceil(cnt/16)*16
{
    const int row = blockIdx.x;          // p*nbatch + b
    const int t   = threadIdx.x;         // one wave
    const int g0  = row * 128 + t;
    const int g1  = g0 + 64;
    const int mk0 = mask[g0], mk1 = mask[g1];
    const unsigned v0 = (unsigned)sig[g0], v1 = (unsigned)sig[g1];

    const unsigned long long b0 = __ballot(mk0 != 0);
    const unsigned long long b1 = __ballot(mk1 != 0);
    const unsigned long long lt = (1ULL << t) - 1ULL;
    const int c0   = __popcll(b0);
    const int cnt  = c0 + __popcll(b1);
    const int pos0 = __popcll(b0 & lt);
    const int pos1 = c0 + __popcll(b1 & lt);

    const unsigned base = (unsigned)row * 128u;
    if (mk0) msig[base + pos0] = v0;
    if (mk1) msig[base + pos1] = v1;

    const int c16 = (cnt + 15) & ~15;
    if (cnt + t < c16) msig[base + cnt + t] = 0u;   // zero-pad (<=15 slots)

    if (t == 0) {
        int c = (cnt < 1) ? 1 : cnt;
        invc[row]  = 1.0f / ((float)c * 1073741823.0f);
        cnt16[row] = (unsigned)c16;
    }
}

__device__ __forceinline__ void acc_elem(unsigned v, unsigned seed,
                                         unsigned long long& sum, unsigned& q) {
    const unsigned long long p2 =
        (unsigned long long)v * (unsigned long long)seed + (unsigned long long)HALF_B;
    const unsigned lo = (unsigned)p2;
    const unsigned hi = (unsigned)(p2 >> 32);
    const unsigned s  = __builtin_amdgcn_alignbit(hi, lo, 31) + (lo & 0x7FFFFFFFu);
    q   += (s >= M31);
    sum += s;
}

__global__ __launch_bounds__(256, 4) void sgnn_main_kernel(
    const unsigned* __restrict__ msig,   // [3, B, 128] compacted
    const float* __restrict__ invc,      // [3, B]
    const unsigned* __restrict__ cnt16,  // [3, B]
    const int* __restrict__ seeds,       // [672]
    float* __restrict__ out,             // [B, 672] == flat[t]
    int nbatch)
{
    const unsigned t = blockIdx.x * 256u + threadIdx.x;  // [0, nbatch*672)
    // b = floor(t/672) = floor((t>>5)/21), exact for t < 2^21 via magic 99865 = ceil(2^21/21)
    const unsigned x = t >> 5;
    const unsigned b = (x * 99865u) >> 21;
    const unsigned h = t - 672u * b;
    const int p = (h < 112u) ? 0 : (h < 336u) ? 1 : 2;

    const unsigned row = (unsigned)(p * nbatch) + b;
    const unsigned* __restrict__ rp = msig + row * 128u;
    const unsigned seed = (unsigned)seeds[h];
    const unsigned n = cnt16[row];                       // multiple of 16, may be 0

    unsigned long long sum0 = 0, sum1 = 0;  // s < 2^32 each; <=128 elems < 2^39, exact
    unsigned q0 = 0, q1 = 0;

    for (unsigned mm = 0; mm < n; mm += 16) {
        const uint4 a = *(const uint4*)(rp + mm);
        const uint4 c = *(const uint4*)(rp + mm + 4);
        const uint4 d = *(const uint4*)(rp + mm + 8);
        const uint4 e = *(const uint4*)(rp + mm + 12);
        acc_elem(a.x, seed, sum0, q0); acc_elem(a.y, seed, sum1, q1);
        acc_elem(a.z, seed, sum0, q0); acc_elem(a.w, seed, sum1, q1);
        acc_elem(c.x, seed, sum0, q0); acc_elem(c.y, seed, sum1, q1);
        acc_elem(c.z, seed, sum0, q0); acc_elem(c.w, seed, sum1, q1);
        acc_elem(d.x, seed, sum0, q0); acc_elem(d.y, seed, sum1, q1);
        acc_elem(d.z, seed, sum0, q0); acc_elem(d.w, seed, sum1, q1);
        acc_elem(e.x, seed, sum0, q0); acc_elem(e.y, seed, sum1, q1);
        acc_elem(e.z, seed, sum0, q0); acc_elem(e.w, seed, sum1, q1);
    }

    const long long centered = (long long)(sum0 + sum1)
                             - (long long)(q0 + q1) * 2147483647LL
                             - (long long)n * 1073741823LL;
    out[t] = (float)centered * invc[row];
}

extern "C" void kernel_launch(void* const* d_in, const int* in_sizes, int n_in,
                              void* d_out, int out_size, void* d_ws, size_t ws_size,
                              hipStream_t stream) {
    const int* sig   = (const int*)d_in[0];
    const int* mask  = (const int*)d_in[1];
    const int* seeds = (const int*)d_in[2];
    float* out = (float*)d_out;

    const int nbatch = in_sizes[0] / (3 * 128);         // 1024
    const int nrows  = 3 * nbatch;                      // 3072
    unsigned* msig  = (unsigned*)d_ws;                                   // nrows*128 u32
    float*    invc  = (float*)((char*)d_ws + (size_t)nrows * 128 * 4);   // nrows f32
    unsigned* c16   = (unsigned*)((char*)d_ws + (size_t)nrows * 132 * 4);// nrows u32

    sgnn_prep_kernel<<<dim3(nrows), dim3(64), 0, stream>>>(sig, mask, msig, invc, c16);
    const int total = nbatch * 672;                     // 688128 = 2688 * 256 exactly
    sgnn_main_kernel<<<dim3(total / 256), dim3(256), 0, stream>>>(msig, invc, c16, seeds, out, nbatch);
}

// Round 7
// 75.497 us; speedup vs baseline: 1.0917x; 1.0136x over previous
//
#include <hip/hip_runtime.h>

// SGNN projection, round 7: cnt4 compaction (-6% elems) + software-pipelined loads.
//
// Math (M = 2^31-1 Mersenne, HALF = 2^30-1):
//   centered(v) = ((v + HALF) mod M) - HALF  ->  p2 = sig*seed + HALF (one v_mad_u64_u32).
//   Fold: s = (p2>>31) + (p2 & M) <= 2^32-4 < 2M ALWAYS (sig,seed <= 2^31-2), so
//   residue = s - M*[s>=M] exactly. centered partial = sum(s) - M*q - n*HALF, exact int64.
//   Pad-zero slots (sig=0) give s = HALF exactly, removed by the n*HALF term.
//
// Compaction: prep packs valid sigs to the row front (ballot prefix-sum), zero-pads
// to cnt4 = ceil(cnt/4)*4 (avg ~92 vs 128 raw, vs 97 for cnt16). Main: pipelined
// step-16 loop (next 4x dwordx4 issued before computing current 16) + step-4 tail.

#define M31    2147483647u   // 2^31 - 1
#define HALF_B 1073741823u   // 2^30 - 1

__global__ __launch_bounds__(64) void sgnn_prep_kernel(
    const int* __restrict__ sig,    // [3, B, 128]
    const int* __restrict__ mask,   // [3, B, 128]
    unsigned* __restrict__ msig,    // [3, B, 128] compacted, zero-padded to cnt4
    float* __restrict__ invc,       // [3, B] = 1/(max(cnt,1)*HALF)
    unsigned* __restrict__ cnt4)    // [3, B] = ceil(cnt/4)*4
{
    const int row = blockIdx.x;          // p*nbatch + b
    const int t   = threadIdx.x;         // one wave
    const int g0  = row * 128 + t;
    const int g1  = g0 + 64;
    const int mk0 = mask[g0], mk1 = mask[g1];
    const unsigned v0 = (unsigned)sig[g0], v1 = (unsigned)sig[g1];

    const unsigned long long b0 = __ballot(mk0 != 0);
    const unsigned long long b1 = __ballot(mk1 != 0);
    const unsigned long long lt = (1ULL << t) - 1ULL;
    const int c0   = __popcll(b0);
    const int cnt  = c0 + __popcll(b1);
    const int pos0 = __popcll(b0 & lt);
    const int pos1 = c0 + __popcll(b1 & lt);

    const unsigned base = (unsigned)row * 128u;
    if (mk0) msig[base + pos0] = v0;
    if (mk1) msig[base + pos1] = v1;

    const int c4 = (cnt + 3) & ~3;
    if (cnt + t < c4) msig[base + cnt + t] = 0u;   // zero-pad (<=3 slots)

    if (t == 0) {
        int c = (cnt < 1) ? 1 : cnt;
        invc[row] = 1.0f / ((float)c * 1073741823.0f);
        cnt4[row] = (unsigned)c4;
    }
}

__device__ __forceinline__ void acc_elem(unsigned v, unsigned seed,
                                         unsigned long long& sum, unsigned& q) {
    const unsigned long long p2 =
        (unsigned long long)v * (unsigned long long)seed + (unsigned long long)HALF_B;
    const unsigned lo = (unsigned)p2;
    const unsigned hi = (unsigned)(p2 >> 32);
    const unsigned s  = __builtin_amdgcn_alignbit(hi, lo, 31) + (lo & 0x7FFFFFFFu);
    q   += (s >= M31);
    sum += s;
}

__device__ __forceinline__ void acc4(uint4 a, unsigned seed,
                                     unsigned long long& s0, unsigned long long& s1,
                                     unsigned& q0, unsigned& q1) {
    acc_elem(a.x, seed, s0, q0); acc_elem(a.y, seed, s1, q1);
    acc_elem(a.z, seed, s0, q0); acc_elem(a.w, seed, s1, q1);
}

__global__ __launch_bounds__(256, 4) void sgnn_main_kernel(
    const unsigned* __restrict__ msig,  // [3, B, 128] compacted
    const float* __restrict__ invc,     // [3, B]
    const unsigned* __restrict__ cnt4,  // [3, B]
    const int* __restrict__ seeds,      // [672]
    float* __restrict__ out,            // [B, 672] == flat[t]
    int nbatch)
{
    const unsigned t = blockIdx.x * 256u + threadIdx.x;  // [0, nbatch*672)
    // b = floor(t/672) = floor((t>>5)/21), exact for t < 2^21 via magic 99865 = ceil(2^21/21)
    const unsigned x = t >> 5;
    const unsigned b = (x * 99865u) >> 21;
    const unsigned h = t - 672u * b;
    const int p = (h < 112u) ? 0 : (h < 336u) ? 1 : 2;

    const unsigned row = (unsigned)(p * nbatch) + b;
    const unsigned* __restrict__ rp = msig + row * 128u;
    const unsigned seed = (unsigned)seeds[h];
    const unsigned n = cnt4[row];        // multiple of 4, may be 0

    unsigned long long sum0 = 0, sum1 = 0;  // s < 2^32 each; <=128 elems < 2^39, exact
    unsigned q0 = 0, q1 = 0;
    unsigned mm = 0;
    const unsigned n16 = n & ~15u;

    if (n16) {
        // software pipeline: loads for group g+1 issue before compute of group g
        uint4 A0 = *(const uint4*)(rp +  0);
        uint4 A1 = *(const uint4*)(rp +  4);
        uint4 A2 = *(const uint4*)(rp +  8);
        uint4 A3 = *(const uint4*)(rp + 12);
        for (mm = 16; mm < n16; mm += 16) {
            const uint4 B0 = *(const uint4*)(rp + mm);
            const uint4 B1 = *(const uint4*)(rp + mm + 4);
            const uint4 B2 = *(const uint4*)(rp + mm + 8);
            const uint4 B3 = *(const uint4*)(rp + mm + 12);
            acc4(A0, seed, sum0, sum1, q0, q1);
            acc4(A1, seed, sum0, sum1, q0, q1);
            acc4(A2, seed, sum0, sum1, q0, q1);
            acc4(A3, seed, sum0, sum1, q0, q1);
            A0 = B0; A1 = B1; A2 = B2; A3 = B3;
        }
        acc4(A0, seed, sum0, sum1, q0, q1);
        acc4(A1, seed, sum0, sum1, q0, q1);
        acc4(A2, seed, sum0, sum1, q0, q1);
        acc4(A3, seed, sum0, sum1, q0, q1);
        mm = n16;
    }
    for (; mm < n; mm += 4) {            // <=3 groups of 4
        const uint4 a = *(const uint4*)(rp + mm);
        acc4(a, seed, sum0, sum1, q0, q1);
    }

    const long long centered = (long long)(sum0 + sum1)
                             - (long long)(q0 + q1) * 2147483647LL
                             - (long long)n * 1073741823LL;
    out[t] = (float)centered * invc[row];
}

extern "C" void kernel_launch(void* const* d_in, const int* in_sizes, int n_in,
                              void* d_out, int out_size, void* d_ws, size_t ws_size,
                              hipStream_t stream) {
    const int* sig   = (const int*)d_in[0];
    const int* mask  = (const int*)d_in[1];
    const int* seeds = (const int*)d_in[2];
    float* out = (float*)d_out;

    const int nbatch = in_sizes[0] / (3 * 128);         // 1024
    const int nrows  = 3 * nbatch;                      // 3072
    unsigned* msig = (unsigned*)d_ws;                                    // nrows*128 u32
    float*    invc = (float*)((char*)d_ws + (size_t)nrows * 128 * 4);    // nrows f32
    unsigned* c4   = (unsigned*)((char*)d_ws + (size_t)nrows * 132 * 4); // nrows u32

    sgnn_prep_kernel<<<dim3(nrows), dim3(64), 0, stream>>>(sig, mask, msig, invc, c4);
    const int total = nbatch * 672;                     // 688128 = 2688 * 256 exactly
    sgnn_main_kernel<<<dim3(total / 256), dim3(256), 0, stream>>>(msig, invc, c4, seeds, out, nbatch);
}